// Round 3
// baseline (1902.530 us; speedup 1.0000x reference)
//
#include <hip/hip_runtime.h>

#define BHX   32      // B*H
#define NSEQ  8192    // sequence length
#define NMASK 8191
#define DIM   64      // head dim
#define NPROJ 7
#define NBUCK 128     // 2^NPROJ
#define NBLK  32      // key blocks of 256
#define QBS   256     // queries per block
#define SSIZE 256     // sampled keys
#define LOG32 3.4657359027997265f

typedef unsigned short u16;
typedef unsigned int   u32;

// ---------------------------------------------------------------------------
// Kernel 1: LSH hash + stable counting sort per (tensor, head)
// grid (2, BHX): blockIdx.x selects q/k; 256 threads.
// bucket = gray(code) = code ^ (code>>1)   (PERM[code] in the reference)
// Output: u16 sorted->original index maps (1 MB total scratch).
// ---------------------------------------------------------------------------
__global__ __launch_bounds__(256) void hash_sort_kernel(
    const float* __restrict__ qg, const float* __restrict__ kg,
    const float* __restrict__ projg,
    u16* __restrict__ qidx, u16* __restrict__ kidx)
{
    const int bh = blockIdx.y;
    const float* __restrict__ x = blockIdx.x ? kg : qg;
    u16* __restrict__ idx       = blockIdx.x ? kidx : qidx;

    __shared__ float projs[NPROJ][DIM];
    __shared__ unsigned char bkts[NSEQ];        // 8 KB
    __shared__ u16 hist[NBUCK][130];            // [bucket][chunk], padded; 33.3 KB
    __shared__ int tot[NBUCK];
    __shared__ int base[NBUCK];

    const int t = threadIdx.x;
    // load projections (448 fp32), transposed to [r][d]
    if (t < 112) {
        #pragma unroll
        for (int u = 0; u < 4; u++) {
            int e = t * 4 + u;
            int d = e / NPROJ, r = e % NPROJ;
            projs[r][d] = projg[e];
        }
    }
    // zero hist (128*130 u16 = 8320 u32)
    u32* hz = (u32*)&hist[0][0];
    for (int z = t; z < (NBUCK * 130) / 2; z += 256) hz[z] = 0u;
    __syncthreads();

    // pass 1: hash 32 rows per thread (sequential-d fp32 accumulation)
    const size_t bhN = (size_t)bh * NSEQ;
    for (int i = 0; i < 32; i++) {
        int n = t * 32 + i;
        const float4* row = (const float4*)(x + (bhN + n) * DIM);
        float dot[NPROJ];
        #pragma unroll
        for (int r = 0; r < NPROJ; r++) dot[r] = 0.0f;
        #pragma unroll
        for (int c = 0; c < 16; c++) {
            float4 w = row[c];
            float f[4] = {w.x, w.y, w.z, w.w};
            #pragma unroll
            for (int u = 0; u < 4; u++) {
                float xv = f[u];
                int d = c * 4 + u;
                #pragma unroll
                for (int r = 0; r < NPROJ; r++) dot[r] += xv * projs[r][d];
            }
        }
        int code = 0;
        #pragma unroll
        for (int r = 0; r < NPROJ; r++) code |= (dot[r] > 0.0f ? 1 : 0) << r;
        bkts[n] = (unsigned char)(code ^ (code >> 1));
    }
    __syncthreads();

    // pass 1b: per-chunk histograms (128 chunks of 64 rows, thread t<128 owns chunk t)
    if (t < NBUCK) {
        for (int i = 0; i < 64; i++) {
            int n = t * 64 + i;
            hist[bkts[n]][t]++;
        }
    }
    __syncthreads();

    // pass 2: per-bucket exclusive scan across chunks
    if (t < NBUCK) {
        u32 run = 0;
        for (int c = 0; c < 128; c++) {
            u32 v = hist[t][c];
            hist[t][c] = (u16)run;
            run += v;
        }
        tot[t] = (int)run;
    }
    __syncthreads();
    if (t == 0) {
        int run = 0;
        for (int b = 0; b < NBUCK; b++) { base[b] = run; run += tot[b]; }
    }
    __syncthreads();

    // pass 3: stable placement
    if (t < NBUCK) {
        for (int i = 0; i < 64; i++) {
            int n = t * 64 + i;
            int b = bkts[n];
            int pos = base[b] + hist[b][t];
            hist[b][t]++;
            idx[bhN + pos] = (u16)n;
        }
    }
}

// ---------------------------------------------------------------------------
// Kernel 2: fused block-diagonal + sampled-residual attention (all fp32).
// grid (NBLK, BHX), 256 threads; thread = one sorted query row.
// Joint online softmax over 256 block keys + 256 sampled keys (+log32, mask).
// ---------------------------------------------------------------------------
__global__ __launch_bounds__(256, 2) void attn_kernel(
    const float* __restrict__ qg, const float* __restrict__ kg,
    const float* __restrict__ vg,
    const u16* __restrict__ qidx, const u16* __restrict__ kidx,
    const int* __restrict__ samp,
    float* __restrict__ outg)
{
    __shared__ float Kt[32][DIM];   // 8 KB
    __shared__ float Vt[32][DIM];   // 8 KB
    __shared__ float addv[32];

    const int qb = blockIdx.x;
    const int bh = blockIdx.y;
    const int t  = threadIdx.x;
    const size_t bhN = (size_t)bh * NSEQ;

    // load my sorted query row into registers
    const int qi = ((int)qidx[bhN + qb * QBS + t]) & NMASK;
    float qreg[DIM];
    {
        const float4* qp = (const float4*)(qg + (bhN + (size_t)qi) * DIM);
        #pragma unroll
        for (int c = 0; c < 16; c++) {
            float4 w = qp[c];
            qreg[c * 4 + 0] = w.x; qreg[c * 4 + 1] = w.y;
            qreg[c * 4 + 2] = w.z; qreg[c * 4 + 3] = w.w;
        }
    }

    float o[DIM];
    #pragma unroll
    for (int d = 0; d < DIM; d++) o[d] = 0.0f;
    float m = -1e30f, l = 0.0f;

    const int r   = t >> 3;   // row in chunk (0..31)
    const int seg = t & 7;    // 8-float segment (0..7)

    for (int cc = 0; cc < 16; cc++) {
        // ---- cooperative load of 32 K/V rows (gathered) ----
        int grow;
        float add;
        if (cc < 8) {
            grow = ((int)kidx[bhN + qb * QBS + cc * 32 + r]) & NMASK;
            add  = 0.0f;
        } else {
            int sidx = samp[bh * SSIZE + (cc - 8) * 32 + r] & NMASK;
            grow = ((int)kidx[bhN + sidx]) & NMASK;
            add  = ((sidx >> 8) == qb) ? -1e30f : LOG32;
        }
        const float4* kp = (const float4*)(kg + (bhN + (size_t)grow) * DIM);
        const float4* vp = (const float4*)(vg + (bhN + (size_t)grow) * DIM);
        float4 k0 = kp[seg * 2], k1 = kp[seg * 2 + 1];
        float4 v0 = vp[seg * 2], v1 = vp[seg * 2 + 1];
        *(float4*)&Kt[r][seg * 8]     = k0;
        *(float4*)&Kt[r][seg * 8 + 4] = k1;
        *(float4*)&Vt[r][seg * 8]     = v0;
        *(float4*)&Vt[r][seg * 8 + 4] = v1;
        if (seg == 0) addv[r] = add;
        __syncthreads();

        // ---- scores for 32 keys ----
        float sreg[32];
        float mc = -1e30f;
        #pragma unroll
        for (int j = 0; j < 32; j++) {
            const float4* kr = (const float4*)(&Kt[j][0]);
            float s0 = 0.f, s1 = 0.f, s2 = 0.f, s3 = 0.f;
            #pragma unroll
            for (int d4 = 0; d4 < 16; d4++) {
                float4 kk = kr[d4];
                s0 += qreg[d4 * 4 + 0] * kk.x;
                s1 += qreg[d4 * 4 + 1] * kk.y;
                s2 += qreg[d4 * 4 + 2] * kk.z;
                s3 += qreg[d4 * 4 + 3] * kk.w;
            }
            float sv = ((s0 + s1) + (s2 + s3)) * 0.125f + addv[j];
            sreg[j] = sv;
            mc = fmaxf(mc, sv);
        }

        // ---- online softmax update ----
        float mn = fmaxf(m, mc);
        float f  = __expf(m - mn);
        l *= f;
        #pragma unroll
        for (int d = 0; d < DIM; d++) o[d] *= f;
        #pragma unroll
        for (int j = 0; j < 32; j++) {
            float p = __expf(sreg[j] - mn);
            l += p;
            const float4* vr = (const float4*)(&Vt[j][0]);
            #pragma unroll
            for (int d4 = 0; d4 < 16; d4++) {
                float4 vv = vr[d4];
                o[d4 * 4 + 0] += p * vv.x;
                o[d4 * 4 + 1] += p * vv.y;
                o[d4 * 4 + 2] += p * vv.z;
                o[d4 * 4 + 3] += p * vv.w;
            }
        }
        m = mn;
        __syncthreads();   // protect LDS before next chunk's overwrite
    }

    // ---- normalize, scatter fp32 to original query position ----
    float inv = 1.0f / fmaxf(l, 1e-30f);
    float4* orow = (float4*)(outg + (bhN + (size_t)qi) * DIM);
    #pragma unroll
    for (int c = 0; c < 16; c++) {
        orow[c] = make_float4(o[c * 4 + 0] * inv, o[c * 4 + 1] * inv,
                              o[c * 4 + 2] * inv, o[c * 4 + 3] * inv);
    }
}

// ---------------------------------------------------------------------------
extern "C" void kernel_launch(void* const* d_in, const int* in_sizes, int n_in,
                              void* d_out, int out_size, void* d_ws, size_t ws_size,
                              hipStream_t stream)
{
    const float* qg   = (const float*)d_in[0];
    const float* kg   = (const float*)d_in[1];
    const float* vg   = (const float*)d_in[2];
    const float* pg   = (const float*)d_in[3];
    const int*   samp = (const int*)d_in[4];
    float* outg = (float*)d_out;

    u16* qidx = (u16*)d_ws;
    u16* kidx = qidx + BHX * NSEQ;

    hipLaunchKernelGGL(hash_sort_kernel, dim3(2, BHX), dim3(256), 0, stream,
                       qg, kg, pg, qidx, kidx);
    hipLaunchKernelGGL(attn_kernel, dim3(NBLK, BHX), dim3(256), 0, stream,
                       qg, kg, vg, qidx, kidx, samp, outg);
}

// Round 4
// 363.966 us; speedup vs baseline: 5.2272x; 5.2272x over previous
//
#include <hip/hip_runtime.h>

#define BHX   32      // B*H
#define NSEQ  8192
#define NMASK 8191
#define DIM   64
#define NPROJ 7
#define NBUCK 128
#define NBLK  32      // key blocks of 256
#define QBS   256
#define SSIZE 256
#define LOG32 3.4657359027997265f
#define KPAD  72      // padded leading dim (bf16 units): 144B, 16B-aligned, bank-spread

typedef unsigned short u16;
typedef unsigned int   u32;
typedef __attribute__((ext_vector_type(8))) short bf16x8;
typedef __attribute__((ext_vector_type(4))) float f32x4;

union B8U { u32 u[4]; bf16x8 v; };

__device__ __forceinline__ u16 f2bf(float f){
    u32 u = __float_as_uint(f);
    u32 r = u + 0x7fffu + ((u >> 16) & 1u);   // RNE
    return (u16)(r >> 16);
}
__device__ __forceinline__ u32 pk2(float a, float b){
    return (u32)f2bf(a) | ((u32)f2bf(b) << 16);
}
__device__ __forceinline__ f32x4 mfma16(bf16x8 a, bf16x8 b, f32x4 c){
    return __builtin_amdgcn_mfma_f32_16x16x32_bf16(a, b, c, 0, 0, 0);
}

// ---------------------------------------------------------------------------
// Kernel 1: LSH hash + stable counting sort (unchanged from passing round 3)
// ---------------------------------------------------------------------------
__global__ __launch_bounds__(256) void hash_sort_kernel(
    const float* __restrict__ qg, const float* __restrict__ kg,
    const float* __restrict__ projg,
    u16* __restrict__ qidx, u16* __restrict__ kidx)
{
    const int bh = blockIdx.y;
    const float* __restrict__ x = blockIdx.x ? kg : qg;
    u16* __restrict__ idx       = blockIdx.x ? kidx : qidx;

    __shared__ float projs[NPROJ][DIM];
    __shared__ unsigned char bkts[NSEQ];
    __shared__ u16 hist[NBUCK][130];
    __shared__ int tot[NBUCK];
    __shared__ int base[NBUCK];

    const int t = threadIdx.x;
    if (t < 112) {
        #pragma unroll
        for (int u = 0; u < 4; u++) {
            int e = t * 4 + u;
            int d = e / NPROJ, r = e % NPROJ;
            projs[r][d] = projg[e];
        }
    }
    u32* hz = (u32*)&hist[0][0];
    for (int z = t; z < (NBUCK * 130) / 2; z += 256) hz[z] = 0u;
    __syncthreads();

    const size_t bhN = (size_t)bh * NSEQ;
    for (int i = 0; i < 32; i++) {
        int n = t * 32 + i;
        const float4* row = (const float4*)(x + (bhN + n) * DIM);
        float dot[NPROJ];
        #pragma unroll
        for (int r = 0; r < NPROJ; r++) dot[r] = 0.0f;
        #pragma unroll
        for (int c = 0; c < 16; c++) {
            float4 w = row[c];
            float f[4] = {w.x, w.y, w.z, w.w};
            #pragma unroll
            for (int u = 0; u < 4; u++) {
                float xv = f[u];
                int d = c * 4 + u;
                #pragma unroll
                for (int r = 0; r < NPROJ; r++) dot[r] += xv * projs[r][d];
            }
        }
        int code = 0;
        #pragma unroll
        for (int r = 0; r < NPROJ; r++) code |= (dot[r] > 0.0f ? 1 : 0) << r;
        bkts[n] = (unsigned char)(code ^ (code >> 1));
    }
    __syncthreads();

    if (t < NBUCK) {
        for (int i = 0; i < 64; i++) hist[bkts[t * 64 + i]][t]++;
    }
    __syncthreads();

    if (t < NBUCK) {
        u32 run = 0;
        for (int c = 0; c < 128; c++) {
            u32 v = hist[t][c];
            hist[t][c] = (u16)run;
            run += v;
        }
        tot[t] = (int)run;
    }
    __syncthreads();
    if (t == 0) {
        int run = 0;
        for (int b = 0; b < NBUCK; b++) { base[b] = run; run += tot[b]; }
    }
    __syncthreads();

    if (t < NBUCK) {
        for (int i = 0; i < 64; i++) {
            int n = t * 64 + i;
            int b = bkts[n];
            int pos = base[b] + hist[b][t];
            hist[b][t]++;
            idx[bhN + pos] = (u16)n;
        }
    }
}

// ---------------------------------------------------------------------------
// Kernel 2: MFMA flash attention over 512 keys (256 block-diag + 256 sampled).
// grid (NBLK, BHX), 256 thr = 4 waves; wave owns 64 sorted queries.
// S^T = K·Q^T  (queries land in C-layout cols -> cheap softmax: 2 shuffles)
// O^T = V^T·P^T (V staged transposed; P via LDS round-trip to B-layout)
// ---------------------------------------------------------------------------
__global__ __launch_bounds__(256, 2) void attn_mfma(
    const float* __restrict__ qg, const float* __restrict__ kg,
    const float* __restrict__ vg,
    const u16* __restrict__ qidx, const u16* __restrict__ kidx,
    const int* __restrict__ samp,
    float* __restrict__ outg)
{
    __shared__ u16  Ks[64 * KPAD];        // [key][d]   9.2 KB
    __shared__ u16  Vt[64 * KPAD];        // [d][key]   9.2 KB
    __shared__ u16  Ps[4 * 64 * KPAD];    // per-wave [query][key] 36.9 KB
    __shared__ float addv[64];

    const int qb = blockIdx.x, bh = blockIdx.y, t = threadIdx.x;
    const int w = t >> 6, lane = t & 63, c = lane & 15, g = lane >> 4;
    const size_t bhN = (size_t)bh * NSEQ;

    // ---- load my wave's 64 query rows as B-fragments (scale folded in) ----
    int qi[4];
    bf16x8 qf[4][2];
    #pragma unroll
    for (int qt = 0; qt < 4; qt++) {
        qi[qt] = ((int)qidx[bhN + qb * QBS + w * 64 + qt * 16 + c]) & NMASK;
        const float* qr = qg + (bhN + (size_t)qi[qt]) * DIM;
        #pragma unroll
        for (int dk = 0; dk < 2; dk++) {
            int d0 = dk * 32 + g * 8;
            float4 x = *(const float4*)(qr + d0);
            float4 y = *(const float4*)(qr + d0 + 4);
            B8U f;
            f.u[0] = pk2(x.x * 0.125f, x.y * 0.125f);
            f.u[1] = pk2(x.z * 0.125f, x.w * 0.125f);
            f.u[2] = pk2(y.x * 0.125f, y.y * 0.125f);
            f.u[3] = pk2(y.z * 0.125f, y.w * 0.125f);
            qf[qt][dk] = f.v;
        }
    }

    f32x4 O[4][4];   // [dt][qt], C layout: row=d, col=query
    #pragma unroll
    for (int dt = 0; dt < 4; dt++)
        #pragma unroll
        for (int qt = 0; qt < 4; qt++) O[dt][qt] = (f32x4)0.0f;
    float m[4] = {-1e30f, -1e30f, -1e30f, -1e30f};
    float l[4] = {0.0f, 0.0f, 0.0f, 0.0f};

    for (int cc = 0; cc < 8; cc++) {
        __syncthreads();   // previous chunk's Ks/Vt reads complete
        // ---- stage 64 keys: K as [key][d] bf16, V transposed [d][key] ----
        {
            int s = t >> 2, seg = (t & 3) * 16;
            int grow; float add;
            if (cc < 4) {
                grow = ((int)kidx[bhN + qb * QBS + cc * 64 + s]) & NMASK;
                add  = 0.0f;
            } else {
                int sidx = samp[bh * SSIZE + (cc - 4) * 64 + s] & NMASK;
                grow = ((int)kidx[bhN + sidx]) & NMASK;
                add  = ((sidx >> 8) == qb) ? -1e30f : LOG32;
            }
            const float4* kr = (const float4*)(kg + (bhN + (size_t)grow) * DIM + seg);
            float4 a = kr[0], b = kr[1], e = kr[2], d = kr[3];
            u32* dst = (u32*)&Ks[s * KPAD + seg];
            dst[0] = pk2(a.x, a.y); dst[1] = pk2(a.z, a.w);
            dst[2] = pk2(b.x, b.y); dst[3] = pk2(b.z, b.w);
            dst[4] = pk2(e.x, e.y); dst[5] = pk2(e.z, e.w);
            dst[6] = pk2(d.x, d.y); dst[7] = pk2(d.z, d.w);
            const float4* vr = (const float4*)(vg + (bhN + (size_t)grow) * DIM + seg);
            float4 va = vr[0], vb = vr[1], vc = vr[2], vd = vr[3];
            float vv[16] = {va.x, va.y, va.z, va.w, vb.x, vb.y, vb.z, vb.w,
                            vc.x, vc.y, vc.z, vc.w, vd.x, vd.y, vd.z, vd.w};
            #pragma unroll
            for (int i = 0; i < 16; i++) Vt[(seg + i) * KPAD + s] = f2bf(vv[i]);
            if ((t & 3) == 0) addv[s] = add;
        }
        __syncthreads();

        // ---- per-lane additive bias for the 4 key rows it holds ----
        f32x4 addn[4];
        #pragma unroll
        for (int kt = 0; kt < 4; kt++)
            addn[kt] = *(const f32x4*)&addv[kt * 16 + g * 4];

        // ---- K A-fragments (reused across 4 qt) ----
        bf16x8 ka[4][2];
        #pragma unroll
        for (int kt = 0; kt < 4; kt++)
            #pragma unroll
            for (int dk = 0; dk < 2; dk++)
                ka[kt][dk] = *(const bf16x8*)&Ks[(kt * 16 + c) * KPAD + dk * 32 + g * 8];

        // ---- S^T per qt: MFMA, online softmax, pack P to LDS ----
        #pragma unroll
        for (int qt = 0; qt < 4; qt++) {
            f32x4 S[4];
            #pragma unroll
            for (int kt = 0; kt < 4; kt++) {
                S[kt] = (f32x4)0.0f;
                S[kt] = mfma16(ka[kt][0], qf[qt][0], S[kt]);
                S[kt] = mfma16(ka[kt][1], qf[qt][1], S[kt]);
            }
            float cmax = -1e30f;
            #pragma unroll
            for (int kt = 0; kt < 4; kt++)
                #pragma unroll
                for (int r = 0; r < 4; r++)
                    cmax = fmaxf(cmax, S[kt][r] + addn[kt][r]);
            cmax = fmaxf(cmax, __shfl_xor(cmax, 16));
            cmax = fmaxf(cmax, __shfl_xor(cmax, 32));
            float mnew  = fmaxf(m[qt], cmax);
            float alpha = __expf(m[qt] - mnew);
            m[qt] = mnew;
            float lsum = 0.0f;
            u16* prow = &Ps[(size_t)(w * 64 + qt * 16 + c) * KPAD];
            #pragma unroll
            for (int kt = 0; kt < 4; kt++) {
                float p0 = __expf(S[kt][0] + addn[kt][0] - mnew);
                float p1 = __expf(S[kt][1] + addn[kt][1] - mnew);
                float p2 = __expf(S[kt][2] + addn[kt][2] - mnew);
                float p3 = __expf(S[kt][3] + addn[kt][3] - mnew);
                lsum += (p0 + p1) + (p2 + p3);
                u32* pw = (u32*)&prow[kt * 16 + g * 4];
                pw[0] = pk2(p0, p1);
                pw[1] = pk2(p2, p3);
            }
            lsum += __shfl_xor(lsum, 16);
            lsum += __shfl_xor(lsum, 32);
            l[qt] = l[qt] * alpha + lsum;
            #pragma unroll
            for (int dt = 0; dt < 4; dt++) O[dt][qt] *= alpha;
        }

        // ---- PV: O^T += V^T · P^T  (two k=32 sub-steps to cap registers) ----
        #pragma unroll
        for (int kk = 0; kk < 2; kk++) {
            bf16x8 vfr[4], pfr[4];
            #pragma unroll
            for (int dt = 0; dt < 4; dt++)
                vfr[dt] = *(const bf16x8*)&Vt[(dt * 16 + c) * KPAD + kk * 32 + g * 8];
            #pragma unroll
            for (int qt = 0; qt < 4; qt++)
                pfr[qt] = *(const bf16x8*)&Ps[(size_t)(w * 64 + qt * 16 + c) * KPAD + kk * 32 + g * 8];
            #pragma unroll
            for (int dt = 0; dt < 4; dt++)
                #pragma unroll
                for (int qt = 0; qt < 4; qt++)
                    O[dt][qt] = mfma16(vfr[dt], pfr[qt], O[dt][qt]);
        }
    }

    // ---- epilogue: normalize, scatter float4 per (qt,dt) ----
    #pragma unroll
    for (int qt = 0; qt < 4; qt++) {
        float inv = 1.0f / fmaxf(l[qt], 1e-30f);
        float* orow = outg + (bhN + (size_t)qi[qt]) * DIM;
        #pragma unroll
        for (int dt = 0; dt < 4; dt++) {
            f32x4 o = O[dt][qt] * inv;
            *(f32x4*)(orow + dt * 16 + g * 4) = o;
        }
    }
}

// ---------------------------------------------------------------------------
extern "C" void kernel_launch(void* const* d_in, const int* in_sizes, int n_in,
                              void* d_out, int out_size, void* d_ws, size_t ws_size,
                              hipStream_t stream)
{
    const float* qg   = (const float*)d_in[0];
    const float* kg   = (const float*)d_in[1];
    const float* vg   = (const float*)d_in[2];
    const float* pg   = (const float*)d_in[3];
    const int*   samp = (const int*)d_in[4];
    float* outg = (float*)d_out;

    u16* qidx = (u16*)d_ws;
    u16* kidx = qidx + BHX * NSEQ;

    hipLaunchKernelGGL(hash_sort_kernel, dim3(2, BHX), dim3(256), 0, stream,
                       qg, kg, pg, qidx, kidx);
    hipLaunchKernelGGL(attn_mfma, dim3(NBLK, BHX), dim3(256), 0, stream,
                       qg, kg, vg, qidx, kidx, samp, outg);
}

// Round 5
// 314.157 us; speedup vs baseline: 6.0560x; 1.1586x over previous
//
#include <hip/hip_runtime.h>

#define BHX   32      // B*H
#define NSEQ  8192
#define NMASK 8191
#define DIM   64
#define NPROJ 7
#define NBUCK 128
#define NBLK  32      // key blocks of 256
#define QBS   256
#define SSIZE 256
#define LOG32 3.4657359027997265f
#define KPAD  72      // padded leading dim (bf16 units)

typedef unsigned short u16;
typedef unsigned int   u32;
typedef unsigned char  u8;
typedef __attribute__((ext_vector_type(8))) short bf16x8;
typedef __attribute__((ext_vector_type(4))) float f32x4;

union B8U { u32 u[4]; bf16x8 v; };

__device__ __forceinline__ u16 f2bf(float f){
    u32 u = __float_as_uint(f);
    u32 r = u + 0x7fffu + ((u >> 16) & 1u);   // RNE
    return (u16)(r >> 16);
}
__device__ __forceinline__ u32 pk2(float a, float b){
    return (u32)f2bf(a) | ((u32)f2bf(b) << 16);
}
__device__ __forceinline__ f32x4 mfma16(bf16x8 a, bf16x8 b, f32x4 c){
    return __builtin_amdgcn_mfma_f32_16x16x32_bf16(a, b, c, 0, 0, 0);
}

// ---------------------------------------------------------------------------
// Kernel 1a: LSH hash. grid (8 slabs, BHX, 2 tensors), 256 thr, 4 rows/thr.
// bucket = gray(code); bytes to ws. Memory-bound (134 MB stream).
// ---------------------------------------------------------------------------
__global__ __launch_bounds__(256) void hash_kernel(
    const float* __restrict__ qg, const float* __restrict__ kg,
    const float* __restrict__ projg,
    u8* __restrict__ bkt)
{
    const int slab = blockIdx.x, bh = blockIdx.y, tz = blockIdx.z;
    const float* __restrict__ x = tz ? kg : qg;
    u8* __restrict__ ob = bkt + ((size_t)tz * BHX + bh) * NSEQ;

    __shared__ float projs[NPROJ][DIM];
    const int t = threadIdx.x;
    if (t < 112) {
        #pragma unroll
        for (int u = 0; u < 4; u++) {
            int e = t * 4 + u;
            projs[e % NPROJ][e / NPROJ] = projg[e];
        }
    }
    __syncthreads();

    const size_t bhN = (size_t)bh * NSEQ;
    #pragma unroll
    for (int j = 0; j < 4; j++) {
        int n = slab * 1024 + j * 256 + t;
        const float4* row = (const float4*)(x + (bhN + n) * DIM);
        float dot[NPROJ];
        #pragma unroll
        for (int r = 0; r < NPROJ; r++) dot[r] = 0.0f;
        #pragma unroll
        for (int c = 0; c < 16; c++) {
            float4 w = row[c];
            float f[4] = {w.x, w.y, w.z, w.w};
            #pragma unroll
            for (int u = 0; u < 4; u++) {
                float xv = f[u];
                int d = c * 4 + u;
                #pragma unroll
                for (int r = 0; r < NPROJ; r++) dot[r] += xv * projs[r][d];
            }
        }
        int code = 0;
        #pragma unroll
        for (int r = 0; r < NPROJ; r++) code |= (dot[r] > 0.0f ? 1 : 0) << r;
        ob[n] = (u8)(code ^ (code >> 1));
    }
}

// ---------------------------------------------------------------------------
// Kernel 1b: stable counting sort per (tensor, head). grid (BHX, 2), 256 thr.
// 256 chunks x 32 elements; hist[bucket][chunk] u16 (66 KB LDS).
// ---------------------------------------------------------------------------
__global__ __launch_bounds__(256) void sort_kernel(
    const u8* __restrict__ bkt,
    u16* __restrict__ qidx, u16* __restrict__ kidx)
{
    const int bh = blockIdx.x, tz = blockIdx.y;
    const u8* __restrict__ ib = bkt + ((size_t)tz * BHX + bh) * NSEQ;
    u16* __restrict__ idx = (tz ? kidx : qidx) + (size_t)bh * NSEQ;

    __shared__ u8  lb[NSEQ];            // 8 KB
    __shared__ u16 hist[NBUCK][258];    // 66 KB, +2 pad
    __shared__ int base[NBUCK];
    __shared__ int tot[NBUCK];

    const int t = threadIdx.x;
    // load bucket bytes (32 B/thread)
    {
        const uint4* src = (const uint4*)ib;
        uint4* dst = (uint4*)lb;
        dst[t] = src[t];
        dst[256 + t] = src[256 + t];
    }
    // zero hist: 128*258 u16 = 16512 u32
    u32* hz = (u32*)&hist[0][0];
    for (int z = t; z < (NBUCK * 258) / 2; z += 256) hz[z] = 0u;
    __syncthreads();

    // per-chunk histogram: thread t owns chunk t (32 elements)
    #pragma unroll 4
    for (int i = 0; i < 32; i++) hist[lb[t * 32 + i]][t]++;
    __syncthreads();

    // exclusive scan over 256 chunks per bucket (128 threads)
    if (t < NBUCK) {
        u32 run = 0;
        for (int c = 0; c < 256; c++) {
            u32 v = hist[t][c];
            hist[t][c] = (u16)run;
            run += v;
        }
        tot[t] = (int)run;
    }
    __syncthreads();
    if (t == 0) {
        int run = 0;
        for (int b = 0; b < NBUCK; b++) { base[b] = run; run += tot[b]; }
    }
    __syncthreads();

    // stable placement: thread t places its chunk in order
    #pragma unroll 4
    for (int i = 0; i < 32; i++) {
        int n = t * 32 + i;
        int b = lb[n];
        int pos = base[b] + hist[b][t];
        hist[b][t]++;
        idx[pos] = (u16)n;
    }
}

// ---------------------------------------------------------------------------
// Kernel 2: MFMA flash attention over 512 keys (256 block-diag + 256 sampled).
// grid (NBLK, BHX), 256 thr = 4 waves; wave owns 64 sorted queries.
// S^T = K·Q^T ; O^T = V^T·P^T (P via LDS round-trip to B-layout)
// ---------------------------------------------------------------------------
__global__ __launch_bounds__(256, 2) void attn_mfma(
    const float* __restrict__ qg, const float* __restrict__ kg,
    const float* __restrict__ vg,
    const u16* __restrict__ qidx, const u16* __restrict__ kidx,
    const int* __restrict__ samp,
    float* __restrict__ outg)
{
    __shared__ u16  Ks[64 * KPAD];        // [key][d]   9.2 KB
    __shared__ u16  Vt[64 * KPAD];        // [d][key]   9.2 KB
    __shared__ u16  Ps[4 * 64 * KPAD];    // per-wave [query][key] 36.9 KB
    __shared__ float addv[64];

    const int qb = blockIdx.x, bh = blockIdx.y, t = threadIdx.x;
    const int w = t >> 6, lane = t & 63, c = lane & 15, g = lane >> 4;
    const size_t bhN = (size_t)bh * NSEQ;

    // ---- load my wave's 64 query rows as B-fragments (scale folded in) ----
    int qi[4];
    bf16x8 qf[4][2];
    #pragma unroll
    for (int qt = 0; qt < 4; qt++) {
        qi[qt] = ((int)qidx[bhN + qb * QBS + w * 64 + qt * 16 + c]) & NMASK;
        const float* qr = qg + (bhN + (size_t)qi[qt]) * DIM;
        #pragma unroll
        for (int dk = 0; dk < 2; dk++) {
            int d0 = dk * 32 + g * 8;
            float4 x = *(const float4*)(qr + d0);
            float4 y = *(const float4*)(qr + d0 + 4);
            B8U f;
            f.u[0] = pk2(x.x * 0.125f, x.y * 0.125f);
            f.u[1] = pk2(x.z * 0.125f, x.w * 0.125f);
            f.u[2] = pk2(y.x * 0.125f, y.y * 0.125f);
            f.u[3] = pk2(y.z * 0.125f, y.w * 0.125f);
            qf[qt][dk] = f.v;
        }
    }

    f32x4 O[4][4];   // [dt][qt], C layout: row=d, col=query
    #pragma unroll
    for (int dt = 0; dt < 4; dt++)
        #pragma unroll
        for (int qt = 0; qt < 4; qt++) O[dt][qt] = (f32x4)0.0f;
    float m[4] = {-1e30f, -1e30f, -1e30f, -1e30f};
    float l[4] = {0.0f, 0.0f, 0.0f, 0.0f};

    for (int cc = 0; cc < 8; cc++) {
        __syncthreads();
        // ---- stage 64 keys: K as [key][d] bf16, V transposed [d][key] ----
        {
            int s = t >> 2, seg = (t & 3) * 16;
            int grow; float add;
            if (cc < 4) {
                grow = ((int)kidx[bhN + qb * QBS + cc * 64 + s]) & NMASK;
                add  = 0.0f;
            } else {
                int sidx = samp[bh * SSIZE + (cc - 4) * 64 + s] & NMASK;
                grow = ((int)kidx[bhN + sidx]) & NMASK;
                add  = ((sidx >> 8) == qb) ? -1e30f : LOG32;
            }
            const float4* kr = (const float4*)(kg + (bhN + (size_t)grow) * DIM + seg);
            float4 a = kr[0], b = kr[1], e = kr[2], d = kr[3];
            u32* dst = (u32*)&Ks[s * KPAD + seg];
            dst[0] = pk2(a.x, a.y); dst[1] = pk2(a.z, a.w);
            dst[2] = pk2(b.x, b.y); dst[3] = pk2(b.z, b.w);
            dst[4] = pk2(e.x, e.y); dst[5] = pk2(e.z, e.w);
            dst[6] = pk2(d.x, d.y); dst[7] = pk2(d.z, d.w);
            const float4* vr = (const float4*)(vg + (bhN + (size_t)grow) * DIM + seg);
            float4 va = vr[0], vb = vr[1], vc = vr[2], vd = vr[3];
            float vv[16] = {va.x, va.y, va.z, va.w, vb.x, vb.y, vb.z, vb.w,
                            vc.x, vc.y, vc.z, vc.w, vd.x, vd.y, vd.z, vd.w};
            #pragma unroll
            for (int i = 0; i < 16; i++) Vt[(seg + i) * KPAD + s] = f2bf(vv[i]);
            if ((t & 3) == 0) addv[s] = add;
        }
        __syncthreads();

        f32x4 addn[4];
        #pragma unroll
        for (int kt = 0; kt < 4; kt++)
            addn[kt] = *(const f32x4*)&addv[kt * 16 + g * 4];

        bf16x8 ka[4][2];
        #pragma unroll
        for (int kt = 0; kt < 4; kt++)
            #pragma unroll
            for (int dk = 0; dk < 2; dk++)
                ka[kt][dk] = *(const bf16x8*)&Ks[(kt * 16 + c) * KPAD + dk * 32 + g * 8];

        #pragma unroll
        for (int qt = 0; qt < 4; qt++) {
            f32x4 S[4];
            #pragma unroll
            for (int kt = 0; kt < 4; kt++) {
                S[kt] = (f32x4)0.0f;
                S[kt] = mfma16(ka[kt][0], qf[qt][0], S[kt]);
                S[kt] = mfma16(ka[kt][1], qf[qt][1], S[kt]);
            }
            float cmax = -1e30f;
            #pragma unroll
            for (int kt = 0; kt < 4; kt++)
                #pragma unroll
                for (int r = 0; r < 4; r++)
                    cmax = fmaxf(cmax, S[kt][r] + addn[kt][r]);
            cmax = fmaxf(cmax, __shfl_xor(cmax, 16));
            cmax = fmaxf(cmax, __shfl_xor(cmax, 32));
            float mnew  = fmaxf(m[qt], cmax);
            float alpha = __expf(m[qt] - mnew);
            m[qt] = mnew;
            float lsum = 0.0f;
            u16* prow = &Ps[(size_t)(w * 64 + qt * 16 + c) * KPAD];
            #pragma unroll
            for (int kt = 0; kt < 4; kt++) {
                float p0 = __expf(S[kt][0] + addn[kt][0] - mnew);
                float p1 = __expf(S[kt][1] + addn[kt][1] - mnew);
                float p2 = __expf(S[kt][2] + addn[kt][2] - mnew);
                float p3 = __expf(S[kt][3] + addn[kt][3] - mnew);
                lsum += (p0 + p1) + (p2 + p3);
                u32* pw = (u32*)&prow[kt * 16 + g * 4];
                pw[0] = pk2(p0, p1);
                pw[1] = pk2(p2, p3);
            }
            lsum += __shfl_xor(lsum, 16);
            lsum += __shfl_xor(lsum, 32);
            l[qt] = l[qt] * alpha + lsum;
            #pragma unroll
            for (int dt = 0; dt < 4; dt++) O[dt][qt] *= alpha;
        }

        #pragma unroll
        for (int kk = 0; kk < 2; kk++) {
            bf16x8 vfr[4], pfr[4];
            #pragma unroll
            for (int dt = 0; dt < 4; dt++)
                vfr[dt] = *(const bf16x8*)&Vt[(dt * 16 + c) * KPAD + kk * 32 + g * 8];
            #pragma unroll
            for (int qt = 0; qt < 4; qt++)
                pfr[qt] = *(const bf16x8*)&Ps[(size_t)(w * 64 + qt * 16 + c) * KPAD + kk * 32 + g * 8];
            #pragma unroll
            for (int dt = 0; dt < 4; dt++)
                #pragma unroll
                for (int qt = 0; qt < 4; qt++)
                    O[dt][qt] = mfma16(vfr[dt], pfr[qt], O[dt][qt]);
        }
    }

    #pragma unroll
    for (int qt = 0; qt < 4; qt++) {
        float inv = 1.0f / fmaxf(l[qt], 1e-30f);
        float* orow = outg + (bhN + (size_t)qi[qt]) * DIM;
        #pragma unroll
        for (int dt = 0; dt < 4; dt++) {
            f32x4 o = O[dt][qt] * inv;
            *(f32x4*)(orow + dt * 16 + g * 4) = o;
        }
    }
}

// ---------------------------------------------------------------------------
extern "C" void kernel_launch(void* const* d_in, const int* in_sizes, int n_in,
                              void* d_out, int out_size, void* d_ws, size_t ws_size,
                              hipStream_t stream)
{
    const float* qg   = (const float*)d_in[0];
    const float* kg   = (const float*)d_in[1];
    const float* vg   = (const float*)d_in[2];
    const float* pg   = (const float*)d_in[3];
    const int*   samp = (const int*)d_in[4];
    float* outg = (float*)d_out;

    u16* qidx = (u16*)d_ws;                       // 512 KB
    u16* kidx = qidx + BHX * NSEQ;                // 512 KB
    u8*  bkt  = (u8*)(kidx + BHX * NSEQ);         // 512 KB

    hipLaunchKernelGGL(hash_kernel, dim3(8, BHX, 2), dim3(256), 0, stream,
                       qg, kg, pg, bkt);
    hipLaunchKernelGGL(sort_kernel, dim3(BHX, 2), dim3(256), 0, stream,
                       bkt, qidx, kidx);
    hipLaunchKernelGGL(attn_mfma, dim3(NBLK, BHX), dim3(256), 0, stream,
                       qg, kg, vg, qidx, kidx, samp, outg);
}